// Round 5
// baseline (274.337 us; speedup 1.0000x reference)
//
#include <hip/hip_runtime.h>
#include <hip/hip_bf16.h>

typedef __attribute__((ext_vector_type(8)))  short bf16x8;   // 8 bf16 = 4 VGPRs
typedef __attribute__((ext_vector_type(16))) float f32x16;   // 32x32 MFMA accumulator

constexpr int Bn = 32, Cn = 64, Hn = 64, Wn = 256, On = 64, En = 4, Rn = 4;
constexpr float SCALE = 1.0f / Rn;

constexpr int WTILE  = 64;          // w per block (was 128)
constexpr int HSTRIP = 8;           // output rows per block
constexpr int SLOT_B = 66 * 128;    // bytes per x-row ring slot (66 ww x 64 c x 2B)

// Ring swizzle: 16B group of c-block cb in slot ww sits at byte
//   ww*128 + ((cb ^ ((ww>>2)&7)) * 16)
// Writes (lane q -> ww=4q+1+j): (ww>>2)&7 covers all 8 groups over q -> conflict-free.
// Reads (lane n -> ww=base+n):  4 consecutive n share a group x8 groups x2 halves
//   = 8 lanes/group = b128 minimum -> conflict-free.
__device__ __forceinline__ int swz(int ww, int cb) {
    return ww * 128 + ((cb ^ ((ww >> 2) & 7)) * 16);
}

// ---------------------------------------------------------------------------
// Merge LoRA into conv weights, in 32x32x16 A-fragment order (unchanged):
// Wfrag[e][mh][s][lane][j]:  o = mh*32 + (lane&31),
//   k: tap = s>>2, c = (s&3)*16 + (lane>>5)*8 + j
// ---------------------------------------------------------------------------
__global__ __launch_bounds__(256) void merge_k(
    const float* __restrict__ Wc, const float* __restrict__ Wa,
    const float* __restrict__ Wb, __hip_bfloat16* __restrict__ Wfrag)
{
    int t = blockIdx.x * 256 + threadIdx.x;          // 0..147455 exact
    int j    = t & 7;
    int lane = (t >> 3) & 63;
    int g    = t >> 9;                               // (e*2+mh)*36 + s
    int s    = g % 36;
    int mh   = (g / 36) & 1;
    int e    = g / 72;
    int m = lane & 31, half = lane >> 5;
    int o = mh * 32 + m;
    int tap = s >> 2, cq = s & 3;
    int c = cq * 16 + half * 8 + j;
    float acc = Wc[(o * Cn + c) * 9 + tap];
#pragma unroll
    for (int r = 0; r < Rn; ++r)
        acc += SCALE * Wb[(e * On + o) * Rn + r] * Wa[((e * Rn + r) * Cn + c) * 9 + tap];
    Wfrag[t] = __float2bfloat16(acc);
}

// ---------------------------------------------------------------------------
// Fused conv, v6: algorithm/schedule of v5 unchanged; concurrency restructure.
// 128-thread blocks (2 waves: mh = wave), WTILE=64 (wave covers 64 w via nf).
// Ring = 4 x 8448 B = 33.8 KB -> 4 blocks/CU x 2 waves = 8 waves/CU in FOUR
// independent 2-wave barrier domains (was two 4-wave domains). Same per-wave
// work: 72 MFMA + 72 ds_read_b128 per iteration.
// ---------------------------------------------------------------------------
__global__ __launch_bounds__(128, 2) void conv6_k(
    const float* __restrict__ x, const int* __restrict__ sid,
    const __hip_bfloat16* __restrict__ Wfrag, float* __restrict__ out)
{
    __shared__ __align__(16) char xs[4 * SLOT_B];        // 33792 B ring

    const int tid = threadIdx.x;                         // 0..127
    const int w0  = blockIdx.x * WTILE;
    const int h0  = blockIdx.y * HSTRIP;
    const int b   = blockIdx.z;
    const int e   = sid[b];
    const size_t HW = (size_t)Hn * Wn;

    const int lane = tid & 63, wave = tid >> 6;          // wave = mh
    const int mh = wave;
    const int n = lane & 31, half = lane >> 5;

    // A fragments: 36 x bf16x8, loaded once (L2-resident), live in VGPRs/AGPRs.
    bf16x8 wf[36];
    const bf16x8* wg = reinterpret_cast<const bf16x8*>(Wfrag) + (size_t)(e * 2 + mh) * 36 * 64;
#pragma unroll
    for (int s = 0; s < 36; ++s) wf[s] = wg[s * 64 + lane];

    // --- staging thread mapping: thread = (cb = tid>>4, w-quad q = tid&15) ---
    const int cb = tid >> 4;                 // c-group 0..7
    const int q  = tid & 15;                 // w-quad 0..15
    const float* xbase = x + ((size_t)b * Cn + cb * 8) * HW + w0 + 4 * q;

    // halo mapping: 32 threads, 4 c each, ds_write_b64
    const int hside = tid >> 4;              // tid<32: 0=left (gw=w0-1), 1=right
    const int hidx  = tid & 15;
    const int hcb   = hidx >> 1, hhi = hidx & 1;
    const int gwh   = hside ? (w0 + WTILE) : (w0 - 1);
    const bool hv   = (unsigned)gwh < (unsigned)Wn;
    const float* hbase = x + ((size_t)b * Cn + hcb * 8 + hhi * 4) * HW + gwh;

    float4 f[8];
    float  hx[4];

    auto stage_load = [&](int rx) {
        const int gh = h0 + rx;
        if ((unsigned)gh < (unsigned)Hn) {
            const float* src = xbase + (size_t)gh * Wn;
#pragma unroll
            for (int r = 0; r < 8; ++r)
                f[r] = *reinterpret_cast<const float4*>(src + r * HW);
            if (tid < 32) {
                if (hv) {
                    const float* hs = hbase + (size_t)gh * Wn;
#pragma unroll
                    for (int i = 0; i < 4; ++i) hx[i] = hs[i * HW];
                } else {
#pragma unroll
                    for (int i = 0; i < 4; ++i) hx[i] = 0.0f;
                }
            }
        } else {
            float4 z4 = make_float4(0.0f, 0.0f, 0.0f, 0.0f);
#pragma unroll
            for (int r = 0; r < 8; ++r) f[r] = z4;
#pragma unroll
            for (int i = 0; i < 4; ++i) hx[i] = 0.0f;
        }
    };
    auto stage_store = [&](int rx) {
        const int slot = (rx + 1) & 3;
        char* dbase = xs + slot * SLOT_B;
#pragma unroll
        for (int j = 0; j < 4; ++j) {
            union { __hip_bfloat16 u[8]; bf16x8 v; } pk;
#pragma unroll
            for (int r = 0; r < 8; ++r) {
                float v = (j == 0) ? f[r].x : (j == 1) ? f[r].y : (j == 2) ? f[r].z : f[r].w;
                pk.u[r] = __float2bfloat16(v);
            }
            int ww = 4 * q + 1 + j;          // 1..64
            *reinterpret_cast<bf16x8*>(dbase + swz(ww, cb)) = pk.v;
        }
        if (tid < 32) {
            union { __hip_bfloat16 u[4]; short4 v; } pk;
#pragma unroll
            for (int i = 0; i < 4; ++i) pk.u[i] = __float2bfloat16(hx[i]);
            int ww = hside ? (WTILE + 1) : 0;        // 65 or 0; (ww>>2)&7 == 0
            *reinterpret_cast<short4*>(dbase + swz(ww, hcb) + hhi * 8) = pk.v;
        }
    };

    auto barrier = [&]() {
        asm volatile("s_waitcnt lgkmcnt(0)" ::: "memory");
        __builtin_amdgcn_s_barrier();
    };

    // prologue: x rows h0-1, h0, h0+1 -> slots 0,1,2
    stage_load(-1); stage_store(-1);
    stage_load(0);  stage_store(0);
    stage_load(1);  stage_store(1);
    barrier();

    for (int st = 0; st < HSTRIP; ++st) {
        // 1. issue next row's global loads (land during compute)
        const bool do_stage = (st + 2 <= HSTRIP);
        if (do_stage) stage_load(st + 2);

        // 2. compute output row h0+st
        f32x16 a[2];
#pragma unroll
        for (int nf = 0; nf < 2; ++nf)
#pragma unroll
            for (int i = 0; i < 16; ++i) a[nf][i] = 0.0f;

#pragma unroll
        for (int s = 0; s < 36; ++s) {
            const int tap = s >> 2, cq = s & 3;
            const int dh = tap / 3, dw = tap % 3;
            const int slotbase = ((st + dh) & 3) * SLOT_B;
#pragma unroll
            for (int nf = 0; nf < 2; ++nf) {
                int ww = nf * 32 + n + dw;                           // 0..65
                bf16x8 bf = *reinterpret_cast<const bf16x8*>(xs + slotbase + swz(ww, cq * 2 + half));
                a[nf] = __builtin_amdgcn_mfma_f32_32x32x16_bf16(wf[s], bf, a[nf], 0, 0, 0);
            }
        }

        // 3. cvt+pack staged row -> ring slot (st+3)&3 (loads had compute to land)
        if (do_stage) stage_store(st + 2);

        // 4. epilogue: direct global stores. For fixed reg: lanes n=0..31 cover
        //    128B contiguous at (o = mh*32 + 4*half + (r&3)+8*(r>>2), row hrow).
        {
            const int hrow = h0 + st;
            size_t base = ((size_t)(b * On + mh * 32 + 4 * half) * Hn + hrow) * Wn
                          + w0 + n;
#pragma unroll
            for (int nf = 0; nf < 2; ++nf)
#pragma unroll
                for (int r = 0; r < 16; ++r) {
                    int o_off = (r & 3) + 8 * (r >> 2);
                    out[base + (size_t)o_off * HW + nf * 32] = a[nf][r];
                }
        }

        // 5. publish staged row / protect ring reuse (LDS-only fence + barrier;
        //    out-stores and next loads stay in flight)
        barrier();
    }
}

// ---------------------------------------------------------------------------
extern "C" void kernel_launch(void* const* d_in, const int* in_sizes, int n_in,
                              void* d_out, int out_size, void* d_ws, size_t ws_size,
                              hipStream_t stream)
{
    const float* x   = (const float*)d_in[0];
    const int*   sid = (const int*)d_in[1];
    const float* Wc  = (const float*)d_in[2];
    const float* Wa  = (const float*)d_in[3];
    const float* Wb  = (const float*)d_in[4];
    float*       out = (float*)d_out;

    __hip_bfloat16* Wfrag = (__hip_bfloat16*)d_ws;   // 294912 B, rewritten each call

    merge_k<<<En * 2 * 36 * 64 * 8 / 256, 256, 0, stream>>>(Wc, Wa, Wb, Wfrag);

    dim3 grid(Wn / WTILE, Hn / HSTRIP, Bn);
    conv6_k<<<grid, 128, 0, stream>>>(x, sid, Wfrag, out);
}

// Round 6
// 273.517 us; speedup vs baseline: 1.0030x; 1.0030x over previous
//
#include <hip/hip_runtime.h>
#include <hip/hip_bf16.h>

typedef __attribute__((ext_vector_type(8)))  short bf16x8;   // 8 bf16 = 4 VGPRs
typedef __attribute__((ext_vector_type(16))) float f32x16;   // 32x32 MFMA accumulator

constexpr int Bn = 32, Cn = 64, Hn = 64, Wn = 256, On = 64, En = 4, Rn = 4;
constexpr float SCALE = 1.0f / Rn;

constexpr int WTILE  = 32;          // w per block
constexpr int HSTRIP = 16;          // output rows per block
constexpr int SLOT_B = 34 * 128;    // bytes per x-row ring slot (34 ww x 64 c x 2B)

// Ring swizzle: 16B group of c-block cb in slot ww sits at byte
//   ww*128 + ((cb ^ ((ww>>2)&7)) * 16)
__device__ __forceinline__ int swz(int ww, int cb) {
    return ww * 128 + ((cb ^ ((ww >> 2) & 7)) * 16);
}

// ---------------------------------------------------------------------------
// Merge LoRA into conv weights, in 32x32x16 A-fragment order (unchanged):
// Wfrag[e][mh][s][lane][j]:  o = mh*32 + (lane&31),
//   k: tap = s>>2, c = (s&3)*16 + (lane>>5)*8 + j
// ---------------------------------------------------------------------------
__global__ __launch_bounds__(256) void merge_k(
    const float* __restrict__ Wc, const float* __restrict__ Wa,
    const float* __restrict__ Wb, __hip_bfloat16* __restrict__ Wfrag)
{
    int t = blockIdx.x * 256 + threadIdx.x;          // 0..147455 exact
    int j    = t & 7;
    int lane = (t >> 3) & 63;
    int g    = t >> 9;                               // (e*2+mh)*36 + s
    int s    = g % 36;
    int mh   = (g / 36) & 1;
    int e    = g / 72;
    int m = lane & 31, half = lane >> 5;
    int o = mh * 32 + m;
    int tap = s >> 2, cq = s & 3;
    int c = cq * 16 + half * 8 + j;
    float acc = Wc[(o * Cn + c) * 9 + tap];
#pragma unroll
    for (int r = 0; r < Rn; ++r)
        acc += SCALE * Wb[(e * On + o) * Rn + r] * Wa[((e * Rn + r) * Cn + c) * 9 + tap];
    Wfrag[t] = __float2bfloat16(acc);
}

// ---------------------------------------------------------------------------
// Fused conv, v8: depth-2 register prefetch.
// 128-thread blocks (2 waves = o-halves), WTILE=32, HSTRIP=16.
// Row r's global loads are issued in iteration r-3 and consumed (cvt+ds_write)
// in iteration r-2 — a FULL iteration in flight. Because loads enter the
// per-wave VMEM queue BEFORE the following epilogue stores, in-order vmcnt
// retirement means the consume-wait never waits on any store.
// Ring 4 x 4352 B = 17.4 KB -> 4 blocks/CU x 2 waves = 8 waves/CU.
// VGPR: wf 144 + acc 16 + fA/fB 32 + misc ~25 = ~220 < 256.
// ---------------------------------------------------------------------------
__global__ __launch_bounds__(128, 2) void conv8_k(
    const float* __restrict__ x, const int* __restrict__ sid,
    const __hip_bfloat16* __restrict__ Wfrag, float* __restrict__ out)
{
    __shared__ __align__(16) char xs[4 * SLOT_B];        // 17408 B ring

    const int tid = threadIdx.x;                         // 0..127
    const int w0  = blockIdx.x * WTILE;
    const int h0  = blockIdx.y * HSTRIP;
    const int b   = blockIdx.z;
    const int e   = sid[b];
    const size_t HW = (size_t)Hn * Wn;

    const int lane = tid & 63, mh = tid >> 6;            // wave = o-half
    const int n = lane & 31, half = lane >> 5;

    // A fragments: 36 x bf16x8, loaded once (L2-resident), live in VGPRs/AGPRs.
    bf16x8 wf[36];
    const bf16x8* wg = reinterpret_cast<const bf16x8*>(Wfrag) + (size_t)(e * 2 + mh) * 36 * 64;
#pragma unroll
    for (int s = 0; s < 36; ++s) wf[s] = wg[s * 64 + lane];

    // staging mapping: thread = (pb = tid>>3 -> planes pb*4..+3, q = tid&7 -> w-quad)
    const int pb = tid >> 3, q = tid & 7;
    const float* xbase = x + ((size_t)b * Cn + pb * 4) * HW + w0 + 4 * q;

    // halo mapping: all 128 threads, side = tid>>6, c = tid&63, one scalar
    const int hside = tid >> 6, hc = tid & 63;
    const int gwh   = hside ? (w0 + WTILE) : (w0 - 1);
    const bool hv   = (unsigned)gwh < (unsigned)Wn;
    const float* hbase = x + ((size_t)b * Cn + hc) * HW + gwh;

    auto stage_load = [&](float4 (&f)[4], float& hx, int rx) {
        const int gh = h0 + rx;
        if ((unsigned)gh < (unsigned)Hn) {
            const float* src = xbase + (size_t)gh * Wn;
#pragma unroll
            for (int r = 0; r < 4; ++r)
                f[r] = *reinterpret_cast<const float4*>(src + r * HW);
            hx = hv ? hbase[(size_t)gh * Wn] : 0.0f;
        } else {
            float4 z4 = make_float4(0.0f, 0.0f, 0.0f, 0.0f);
#pragma unroll
            for (int r = 0; r < 4; ++r) f[r] = z4;
            hx = 0.0f;
        }
    };
    auto stage_store = [&](float4 (&f)[4], float& hx, int rx) {
        const int slot = (rx + 1) & 3;
        char* dbase = xs + slot * SLOT_B;
        const int cb = pb >> 1, sub = (pb & 1) * 8;      // half of 16B c-group
#pragma unroll
        for (int j = 0; j < 4; ++j) {
            union { __hip_bfloat16 u[4]; short4 v; } pk;
#pragma unroll
            for (int r = 0; r < 4; ++r) {
                float v = (j == 0) ? f[r].x : (j == 1) ? f[r].y : (j == 2) ? f[r].z : f[r].w;
                pk.u[r] = __float2bfloat16(v);
            }
            int ww = 4 * q + 1 + j;                      // 1..32
            *reinterpret_cast<short4*>(dbase + swz(ww, cb) + sub) = pk.v;
        }
        {   // halo: 2B store, c = hc
            __hip_bfloat16 hb = __float2bfloat16(hx);
            int ww = hside ? (WTILE + 1) : 0;            // 33 or 0
            *reinterpret_cast<__hip_bfloat16*>(dbase + swz(ww, hc >> 3) + (hc & 7) * 2) = hb;
        }
    };

    auto barrier = [&]() {
        asm volatile("s_waitcnt lgkmcnt(0)" ::: "memory");
        __builtin_amdgcn_s_barrier();
    };

    float4 fA[4], fB[4];
    float  hxA, hxB;

    // prologue: rows -1,0,1 staged serially (bank A); row 2 loads left in flight
    // in bank A (row r lives in bank r&1; 2&1==0 -> A).
    stage_load(fA, hxA, -1); stage_store(fA, hxA, -1);
    stage_load(fA, hxA, 0);  stage_store(fA, hxA, 0);
    stage_load(fA, hxA, 1);  stage_store(fA, hxA, 1);
    stage_load(fA, hxA, 2);
    barrier();

    for (int st = 0; st < HSTRIP; ++st) {
        // 1. issue row st+3 into the opposite bank (consumed next iteration)
        const bool do_issue = (st + 3 <= HSTRIP);
        if (do_issue) {
            if (st & 1) stage_load(fA, hxA, st + 3);
            else        stage_load(fB, hxB, st + 3);
        }

        // 2. compute output row h0+st
        f32x16 a;
#pragma unroll
        for (int i = 0; i < 16; ++i) a[i] = 0.0f;

#pragma unroll
        for (int s = 0; s < 36; ++s) {
            const int tap = s >> 2, cq = s & 3;
            const int dh = tap / 3, dw = tap % 3;
            const int slotbase = ((st + dh) & 3) * SLOT_B;
            int ww = n + dw;                              // 0..33
            bf16x8 bf = *reinterpret_cast<const bf16x8*>(xs + slotbase + swz(ww, cq * 2 + half));
            a = __builtin_amdgcn_mfma_f32_32x32x16_bf16(wf[s], bf, a, 0, 0, 0);
        }

        // 3. consume row st+2 (loaded LAST iteration; its loads are older than
        //    any store in the queue -> wait never drains stores)
        const bool do_store = (st + 2 <= HSTRIP);
        if (do_store) {
            if (st & 1) stage_store(fB, hxB, st + 2);
            else        stage_store(fA, hxA, st + 2);
        }

        // 4. epilogue: direct global stores. Lanes n=0..31 cover 128B contiguous
        //    at (o = mh*32 + 4*half + (r&3)+8*(r>>2), row hrow).
        {
            const int hrow = h0 + st;
            size_t base = ((size_t)(b * On + mh * 32 + 4 * half) * Hn + hrow) * Wn + w0 + n;
#pragma unroll
            for (int r = 0; r < 16; ++r) {
                int o_off = (r & 3) + 8 * (r >> 2);
                out[base + (size_t)o_off * HW] = a[r];
            }
        }

        // 5. publish staged row / protect ring reuse (LDS fence + barrier only)
        barrier();
    }
}

// ---------------------------------------------------------------------------
extern "C" void kernel_launch(void* const* d_in, const int* in_sizes, int n_in,
                              void* d_out, int out_size, void* d_ws, size_t ws_size,
                              hipStream_t stream)
{
    const float* x   = (const float*)d_in[0];
    const int*   sid = (const int*)d_in[1];
    const float* Wc  = (const float*)d_in[2];
    const float* Wa  = (const float*)d_in[3];
    const float* Wb  = (const float*)d_in[4];
    float*       out = (float*)d_out;

    __hip_bfloat16* Wfrag = (__hip_bfloat16*)d_ws;   // 294912 B, rewritten each call

    merge_k<<<En * 2 * 36 * 64 * 8 / 256, 256, 0, stream>>>(Wc, Wa, Wb, Wfrag);

    dim3 grid(Wn / WTILE, Hn / HSTRIP, Bn);
    conv8_k<<<grid, 128, 0, stream>>>(x, sid, Wfrag, out);
}